// Round 9
// baseline (199.287 us; speedup 1.0000x reference)
//
#include <hip/hip_runtime.h>
#include <float.h>

typedef _Float16 half8 __attribute__((ext_vector_type(8)));
typedef float    f32x4  __attribute__((ext_vector_type(4)));
typedef float    f32x16 __attribute__((ext_vector_type(16)));

// Problem constants
constexpr int N_TOK = 65536;        // 16*64*64 tokens
constexpr int D     = 64;           // embedding dim
constexpr int K     = 2048;         // codebook size
constexpr int TILE_C = 64;          // codes per tile
constexpr int NTILE  = K / TILE_C;  // 32
constexpr int TOK_PER_BLK = 64;     // tokens per fused block
constexpr int NBLK = N_TOK / TOK_PER_BLK;    // 1024 fused blocks
constexpr float EPS_RESCORE = 2e-3f; // belt >= 2*(split err 4e-5 + 32ulp(128) 4.9e-4)

// Output layout (all float32, concatenated in reference return order)
constexpr size_t QN       = (size_t)N_TOK * D;
constexpr size_t SCAL_OFF = QN;
constexpr size_t IDX_OFF  = QN + 5;
constexpr size_t PROB_OFF = IDX_OFF + N_TOK;

// Workspace layout (bytes), total ~537 KB
constexpr size_t WS_HNORM = 0;                          // [K] f32  0.5*||c||^2
constexpr size_t WS_COUNT = 8192;                       // [K] u32
constexpr size_t WS_BSUM  = 16384;                      // [1024] double
constexpr size_t WS_SW    = 24576;                      // [NTILE][2 ct][64 lane][8] half8 frag image (32x32 shape)

__device__ inline unsigned long long pack_key(float d, int k) {
    unsigned u = __float_as_uint(d);
    u = (u & 0x80000000u) ? ~u : (u | 0x80000000u);   // monotone float->uint
    return ((unsigned long long)u << 32) | (unsigned)k;
}

__device__ inline float unpack_dist(unsigned long long key) {
    unsigned u = (unsigned)(key >> 32);
    u = (u & 0x80000000u) ? (u & 0x7FFFFFFFu) : ~u;   // inverse monotone map
    return __uint_as_float(u);
}

__device__ inline unsigned long long shfl_xor_u64_w32(unsigned long long v, int m) {
    int lo = __shfl_xor((int)(unsigned)v, m, 32);
    int hi = __shfl_xor((int)(unsigned)(v >> 32), m, 32);
    return ((unsigned long long)(unsigned)hi << 32) | (unsigned)lo;
}

// One thread per (code row r, 8-elem chunk c0). Frag image for the 32x32x16
// MFMA shape: per tile t (64 codes = 2 code-tiles ct of 32), consumer lane l
// (col=l&31 -> code ct*32+col, h5=l>>5 -> k-half) needs 8 half8 fragments:
// hi kk=0..3 then lo kk=0..3, element k = kk*16 + h5*8 + j. Stored per-lane
// CONTIGUOUS 128 B:  sw[((t*2+ct)*64 + l)*8 + f]   (f<4: hi kk=f; f>=4: lo).
// Producer (r,c0): elements [8c0,8c0+8) -> kk=c0>>1, half=c0&1,
// lane=(c0&1)*32+(r&31), t=r>>6, ct=(r>>5)&1.
__global__ __launch_bounds__(256) void vq_init(const float* __restrict__ emb,
                                               float* __restrict__ hnorm,
                                               unsigned* __restrict__ counts,
                                               double* __restrict__ blocksums,
                                               half8* __restrict__ sw) {
    const int g  = blockIdx.x * 256 + threadIdx.x;   // 0..16383
    const int r  = g >> 3;                           // code row
    const int c0 = g & 7;                            // chunk within row
    const float4* p4 = (const float4*)(emb + (size_t)r * D + 8 * c0);
    float4 q0 = p4[0], q1 = p4[1];
    float v[8] = {q0.x, q0.y, q0.z, q0.w, q1.x, q1.y, q1.z, q1.w};
    half8 h, l;
    float s = 0.f;
#pragma unroll
    for (int i = 0; i < 8; ++i) {
        s += v[i] * v[i];
        _Float16 hh = (_Float16)v[i];
        h[i] = hh;
        l[i] = (_Float16)(v[i] - (float)hh);
    }
    const int t    = r >> 6;
    const int ct   = (r >> 5) & 1;
    const int lane = (c0 & 1) * 32 + (r & 31);
    const int f    = c0 >> 1;
    half8* dst = sw + ((size_t)((t * 2 + ct) * 64 + lane)) * 8;
    dst[f]     = h;   // hi fragment kk=f
    dst[4 + f] = l;   // lo fragment kk=f

#pragma unroll
    for (int off = 1; off < 8; off <<= 1) s += __shfl_xor(s, off, 8);
    if (c0 == 0) hnorm[r] = 0.5f * s;
    if (g < K) counts[g] = 0u;
    if (g < NBLK) blocksums[g] = 0.0;
}

// Load one tile's 8 fragments (contiguous 128 B/lane) + code half-norm.
#define LOADB(TOFF, H0, H1, H2, H3, L0, L1, L2, L3, HN)                            \
  {                                                                                \
    const half8* _q = pb + (TOFF) * 1024;                                          \
    H0 = _q[0]; H1 = _q[1]; H2 = _q[2]; H3 = _q[3];                                \
    L0 = _q[4]; L1 = _q[5]; L2 = _q[6]; L3 = _q[7];                                \
    HN = ph[(TOFF) * 64];                                                          \
  }

// 12 chained 32x32x16 MFMAs into one f32x16 acc initialized with hn (hn is
// per-code = per-lane-col, identical across the 16 output regs). Terms:
// hh(4 K-chunks) + lh(4) + hl(4); ll dropped (~1e-6). Min-tracking packs the
// 5-bit tile index into the low mantissa bits (<=32 ulp(128) ~ 4.9e-4 << belt).
#define VQ_STEP(H0, H1, H2, H3, L0, L1, L2, L3, HN, TT)                            \
  {                                                                                \
    f32x16 acc;                                                                    \
    _Pragma("unroll")                                                              \
    for (int i = 0; i < 16; ++i) acc[i] = (HN);                                    \
    __builtin_amdgcn_s_setprio(1);                                                 \
    acc = __builtin_amdgcn_mfma_f32_32x32x16_f16(axh[0], H0, acc, 0, 0, 0);        \
    acc = __builtin_amdgcn_mfma_f32_32x32x16_f16(axh[1], H1, acc, 0, 0, 0);        \
    acc = __builtin_amdgcn_mfma_f32_32x32x16_f16(axh[2], H2, acc, 0, 0, 0);        \
    acc = __builtin_amdgcn_mfma_f32_32x32x16_f16(axh[3], H3, acc, 0, 0, 0);        \
    acc = __builtin_amdgcn_mfma_f32_32x32x16_f16(axl[0], H0, acc, 0, 0, 0);        \
    acc = __builtin_amdgcn_mfma_f32_32x32x16_f16(axl[1], H1, acc, 0, 0, 0);        \
    acc = __builtin_amdgcn_mfma_f32_32x32x16_f16(axl[2], H2, acc, 0, 0, 0);        \
    acc = __builtin_amdgcn_mfma_f32_32x32x16_f16(axl[3], H3, acc, 0, 0, 0);        \
    acc = __builtin_amdgcn_mfma_f32_32x32x16_f16(axh[0], L0, acc, 0, 0, 0);        \
    acc = __builtin_amdgcn_mfma_f32_32x32x16_f16(axh[1], L1, acc, 0, 0, 0);        \
    acc = __builtin_amdgcn_mfma_f32_32x32x16_f16(axh[2], L2, acc, 0, 0, 0);        \
    acc = __builtin_amdgcn_mfma_f32_32x32x16_f16(axh[3], L3, acc, 0, 0, 0);        \
    __builtin_amdgcn_s_setprio(0);                                                 \
    _Pragma("unroll")                                                              \
    for (int i = 0; i < 16; ++i) {                                                 \
      unsigned _kb = (__float_as_uint(acc[i]) & 0xFFFFFFE0u) | (unsigned)(TT);     \
      best_d[i] = fminf(best_d[i], __uint_as_float(_kb));                          \
    }                                                                              \
  }

// Fused: one block = 64 tokens x ALL 2048 codes, 32x32x16 MFMA shape.
// 4 waves split (token-half tt x code-half ct): each wave = 32 tokens x 32
// codes per step = 12 MFMAs (vs 24 with 16x16x32) -- halves MFMA instruction
// count and per-step issue pressure, 2x MACs per B fragment, ~15% better
// MFMA rate. Barrier-free R4-style even/odd register double-buffer.
__global__ __launch_bounds__(256) void vq_fused(const float* __restrict__ x,
                                                const float* __restrict__ emb,
                                                const float* __restrict__ hnorm,
                                                const half8* __restrict__ sw,
                                                unsigned* __restrict__ counts,
                                                double* __restrict__ blocksums,
                                                float* __restrict__ out) {
    __shared__ unsigned long long kls[64][3];         // 2 candidates + pad
    __shared__ int bks[64];
    __shared__ double wsum[4];

    const int tid  = threadIdx.x;
    const int lane = tid & 63;
    const int wav  = tid >> 6;
    const int t0   = blockIdx.x * TOK_PER_BLK;
    const int col  = lane & 31;             // A row (token) / B col (code) in 32-tile
    const int h5   = lane >> 5;             // k-half (0..1)
    const int tt   = wav >> 1;              // token-half (0..1)
    const int ct   = wav & 1;               // code-half  (0..1)

    // A fragments: this wave's 32 tokens (row=col), negated hi/lo fp16 split.
    // k = kk*16 + h5*8 + j  ->  read 8 floats at x[token*64 + h5*8 + kk*16].
    half8 axh[4], axl[4];
    {
        const float* xr = x + (size_t)(t0 + tt * 32 + col) * D + h5 * 8;
#pragma unroll
        for (int kk = 0; kk < 4; ++kk) {
            const float4* p4 = (const float4*)(xr + kk * 16);
            float4 q0 = p4[0], q1 = p4[1];
            float v[8] = {q0.x, q0.y, q0.z, q0.w, q1.x, q1.y, q1.z, q1.w};
            half8 h, l;
#pragma unroll
            for (int j = 0; j < 8; ++j) {
                float nv = -v[j];
                _Float16 hh = (_Float16)nv;
                h[j] = hh;
                l[j] = (_Float16)(nv - (float)hh);
            }
            axh[kk] = h; axl[kk] = l;
        }
    }

    float best_d[16];                       // packed keys: dist w/ tile idx in low 5 bits
#pragma unroll
    for (int i = 0; i < 16; ++i) best_d[i] = FLT_MAX;

    // per-lane streaming pointers: 128 B of fragments per lane per tile
    const half8* pb = sw + (size_t)(ct * 64 + lane) * 8;  // + tile*1024 half8
    const float* ph = hnorm + ct * 32 + col;              // + tile*64 floats

    half8 eH0, eH1, eH2, eH3, eL0, eL1, eL2, eL3;  float hE;   // even tiles
    half8 oH0, oH1, oH2, oH3, oL0, oL1, oL2, oL3;  float hO;   // odd tiles

    // prologue: tile 0
    LOADB(0, eH0, eH1, eH2, eH3, eL0, eL1, eL2, eL3, hE);

    for (int t = 0; t < NTILE; t += 2) {
        LOADB(1, oH0, oH1, oH2, oH3, oL0, oL1, oL2, oL3, hO);   // tile t+1
        VQ_STEP(eH0, eH1, eH2, eH3, eL0, eL1, eL2, eL3, hE, t);
        if (t + 2 < NTILE)
            LOADB(2, eH0, eH1, eH2, eH3, eL0, eL1, eL2, eL3, hE);  // tile t+2
        VQ_STEP(oH0, oH1, oH2, oH3, oL0, oL1, oL2, oL3, hO, t + 1);
        pb += 2048; ph += 128;
    }

    // recover code; reduce each output row over its 32 code-columns.
    // D layout (32x32, HW-verified): col=lane&31, row=(reg&3)+8*(reg>>2)+4*h5.
#pragma unroll
    for (int reg = 0; reg < 16; ++reg) {
        const unsigned bits = __float_as_uint(best_d[reg]);
        const int code = (int)(bits & 31u) * TILE_C + ct * 32 + col;
        unsigned long long key = pack_key(best_d[reg], code);
#pragma unroll
        for (int off = 16; off; off >>= 1) {
            unsigned long long o = shfl_xor_u64_w32(key, off);
            if (o < key) key = o;
        }
        if (col == 0) {
            const int tl = tt * 32 + (reg & 3) + 8 * (reg >> 2) + 4 * h5;
            kls[tl][ct] = key;
        }
    }
    __syncthreads();

    // merge the 2 code-half winners per token (wave 0, one lane per token)
    if (tid < 64) {
        unsigned long long k0 = kls[tid][0];
        unsigned long long k1 = kls[tid][1];
        const float d0 = unpack_dist(k0), d1 = unpack_dist(k1);
        unsigned long long kmin = (k0 < k1) ? k0 : k1;
        int bk = (int)(unsigned)(kmin & 0xFFFFFFFFu);
        const float fmin = unpack_dist(kmin);

        if (d0 <= fmin + EPS_RESCORE && d1 <= fmin + EPS_RESCORE) {
            // near-tie across halves: exact fp32 rescore of both candidates
            unsigned long long bkey = ~0ULL;   // smaller dist, tie smaller k
            const float* xr = x + (size_t)(t0 + tid) * D;
            const int cand[2] = {(int)(unsigned)(k0 & 0xFFFFFFFFu),
                                 (int)(unsigned)(k1 & 0xFFFFFFFFu)};
#pragma unroll
            for (int w = 0; w < 2; ++w) {
                const int k = cand[w];
                const float* cr = emb + (size_t)k * D;
                float s0 = 0.f, s1 = 0.f, s2 = 0.f, s3 = 0.f;
#pragma unroll
                for (int i = 0; i < 16; ++i) {
                    s0 = fmaf(cr[4 * i + 0], xr[4 * i + 0], s0);
                    s1 = fmaf(cr[4 * i + 1], xr[4 * i + 1], s1);
                    s2 = fmaf(cr[4 * i + 2], xr[4 * i + 2], s2);
                    s3 = fmaf(cr[4 * i + 3], xr[4 * i + 3], s3);
                }
                float hd = hnorm[k] - ((s0 + s1) + (s2 + s3));
                unsigned long long key = pack_key(hd, k);
                if (key < bkey) bkey = key;
            }
            bk = (int)(unsigned)(bkey & 0xFFFFFFFFu);
        }
        bks[tid] = bk;
        out[IDX_OFF + t0 + tid] = (float)bk;
        atomicAdd(&counts[bk], 1u);
    }
    __syncthreads();

    // inline epilogue: quantize + sumsq (4 threads per token, coalesced)
    const int tok = tid >> 2;
    const int i4  = tid & 3;
    const int bk  = bks[tok];
    const float4* xr4 = (const float4*)(x + (size_t)(t0 + tok) * D);
    const float4* cr4 = (const float4*)(emb + (size_t)bk * D);
    float4* qr4 = (float4*)(out + (size_t)(t0 + tok) * D);
    float local = 0.f;
#pragma unroll
    for (int ii = 0; ii < 4; ++ii) {
        const int idx = i4 + 4 * ii;
        float4 xv = xr4[idx];
        float4 cv = cr4[idx];
        float dx = cv.x - xv.x, dy = cv.y - xv.y;
        float dz = cv.z - xv.z, dw = cv.w - xv.w;
        local += dx * dx + dy * dy + dz * dz + dw * dw;
        float4 q;
        q.x = xv.x + dx; q.y = xv.y + dy;   // straight-through: x + (q - x)
        q.z = xv.z + dz; q.w = xv.w + dw;
        qr4[idx] = q;
    }
    double ld = (double)local;
#pragma unroll
    for (int off = 32; off > 0; off >>= 1) ld += __shfl_down(ld, off, 64);
    if (lane == 0) wsum[wav] = ld;
    __syncthreads();
    if (tid == 0)
        blocksums[blockIdx.x] = (wsum[0] + wsum[1]) + (wsum[2] + wsum[3]);
}

__global__ __launch_bounds__(256) void vq_finalize(const unsigned* __restrict__ counts,
                                                   const double* __restrict__ blocksums,
                                                   float* __restrict__ out) {
    const int tid = threadIdx.x;
    double e = 0.0;
#pragma unroll
    for (int i = 0; i < 8; ++i) {
        int k = tid + i * 256;
        float p = (float)counts[k] / 65536.0f;
        out[PROB_OFF + k] = p;
        double pd = (double)p;
        e += pd * log(pd + 1e-5);
    }
    double s = 0.0;
#pragma unroll
    for (int i = 0; i < NBLK / 256; ++i) s += blocksums[tid + i * 256];
#pragma unroll
    for (int off = 32; off > 0; off >>= 1) {
        e += __shfl_down(e, off, 64);
        s += __shfl_down(s, off, 64);
    }
    __shared__ double we[4], ws2[4];
    int lane = tid & 63, wid = tid >> 6;
    if (lane == 0) { we[wid] = e; ws2[wid] = s; }
    __syncthreads();
    if (tid == 0) {
        double entropy = (we[0] + we[1]) + (we[2] + we[3]);
        double sumsq   = (ws2[0] + ws2[1]) + (ws2[2] + ws2[3]);
        double mse     = sumsq / (double)((size_t)N_TOK * D);
        out[SCAL_OFF + 0] = (float)(1.25 * mse + 0.1 * entropy); // vq_loss
        out[SCAL_OFF + 1] = (float)mse;                          // commitment_loss
        out[SCAL_OFF + 2] = (float)mse;                          // codebook_loss
        out[SCAL_OFF + 3] = (float)exp(-entropy);                // perplexity
        out[SCAL_OFF + 4] = (float)entropy;                      // entropy_loss
    }
}

extern "C" void kernel_launch(void* const* d_in, const int* in_sizes, int n_in,
                              void* d_out, int out_size, void* d_ws, size_t ws_size,
                              hipStream_t stream) {
    const float* x   = (const float*)d_in[0];
    const float* emb = (const float*)d_in[1];
    float* out = (float*)d_out;

    char* ws = (char*)d_ws;
    float*    hnorm     = (float*)(ws + WS_HNORM);
    unsigned* counts    = (unsigned*)(ws + WS_COUNT);
    double*   blocksums = (double*)(ws + WS_BSUM);
    half8*    sw        = (half8*)(ws + WS_SW);

    vq_init<<<K * 8 / 256, 256, 0, stream>>>(emb, hnorm, counts, blocksums, sw);
    vq_fused<<<NBLK, 256, 0, stream>>>(x, emb, hnorm, sw, counts, blocksums, out);
    vq_finalize<<<1, 256, 0, stream>>>(counts, blocksums, out);
}

// Round 10
// 133.794 us; speedup vs baseline: 1.4895x; 1.4895x over previous
//
#include <hip/hip_runtime.h>
#include <float.h>

typedef _Float16 half8 __attribute__((ext_vector_type(8)));
typedef float    f32x4 __attribute__((ext_vector_type(4)));

// Problem constants
constexpr int N_TOK = 65536;        // 16*64*64 tokens
constexpr int D     = 64;           // embedding dim
constexpr int K     = 2048;         // codebook size
constexpr int TILE_C = 64;          // codes per tile
constexpr int NTILE  = K / TILE_C;  // 32
constexpr int TOK_PER_BLK = 64;     // tokens per fused block
constexpr int NBLK = N_TOK / TOK_PER_BLK;    // 1024 fused blocks
constexpr float EPS_RESCORE = 2e-3f; // belt >> pruner error (~1e-4) + key quant (~1.2e-4)

// Output layout (all float32, concatenated in reference return order)
constexpr size_t QN       = (size_t)N_TOK * D;
constexpr size_t SCAL_OFF = QN;
constexpr size_t IDX_OFF  = QN + 5;
constexpr size_t PROB_OFF = IDX_OFF + N_TOK;

// Workspace layout (bytes), total ~537 KB
constexpr size_t WS_HNORM = 0;                          // [K] f32  0.5*||c||^2
constexpr size_t WS_COUNT = 8192;                       // [K] u32
constexpr size_t WS_BSUM  = 16384;                      // [1024] double
constexpr size_t WS_SW    = 24576;                      // [NTILE][256][4] half8 per-lane frag image

__device__ inline unsigned long long pack_key(float d, int k) {
    unsigned u = __float_as_uint(d);
    u = (u & 0x80000000u) ? ~u : (u | 0x80000000u);   // monotone float->uint
    return ((unsigned long long)u << 32) | (unsigned)k;
}

__device__ inline float unpack_dist(unsigned long long key) {
    unsigned u = (unsigned)(key >> 32);
    u = (u & 0x80000000u) ? (u & 0x7FFFFFFFu) : ~u;   // inverse monotone map
    return __uint_as_float(u);
}

__device__ inline unsigned long long shfl_xor_u64_w16(unsigned long long v, int m) {
    int lo = __shfl_xor((int)(unsigned)v, m, 16);
    int hi = __shfl_xor((int)(unsigned)(v >> 32), m, 16);
    return ((unsigned long long)(unsigned)hi << 32) | (unsigned)lo;
}

// One thread per (code row r, 8-elem chunk c0). Frag image: per tile, the 4
// MFMA B-fragments a consumer lane needs are CONTIGUOUS 64 B:
//   sw[(t*256 + tid)*4 + slot]  (half8), consumer tid = w*64+l, g=l>>4,
//   m16=l&15, code = t*64 + w*16 + m16,
//   slots = {hi chunk g, hi chunk g+4, lo chunk g, lo chunk g+4}.
__global__ __launch_bounds__(256) void vq_init(const float* __restrict__ emb,
                                               float* __restrict__ hnorm,
                                               unsigned* __restrict__ counts,
                                               double* __restrict__ blocksums,
                                               half8* __restrict__ sw) {
    const int g  = blockIdx.x * 256 + threadIdx.x;   // 0..16383
    const int r  = g >> 3;                           // code row
    const int c0 = g & 7;                            // chunk within row
    const float4* p4 = (const float4*)(emb + (size_t)r * D + 8 * c0);
    float4 q0 = p4[0], q1 = p4[1];
    float v[8] = {q0.x, q0.y, q0.z, q0.w, q1.x, q1.y, q1.z, q1.w};
    half8 h, l;
    float s = 0.f;
#pragma unroll
    for (int i = 0; i < 8; ++i) {
        s += v[i] * v[i];
        _Float16 hh = (_Float16)v[i];
        h[i] = hh;
        l[i] = (_Float16)(v[i] - (float)hh);
    }
    const int t    = r >> 6;
    const int w    = (r >> 4) & 3;
    const int m16  = r & 15;
    const int lane = (c0 & 3) * 16 + m16;
    const int slot = c0 >> 2;
    half8* dst = sw + ((size_t)(t * 256 + w * 64 + lane)) * 4;
    dst[slot]     = h;   // hi fragment
    dst[2 + slot] = l;   // lo fragment

#pragma unroll
    for (int off = 1; off < 8; off <<= 1) s += __shfl_xor(s, off, 8);
    if (c0 == 0) hnorm[r] = 0.5f * s;
    if (g < K) counts[g] = 0u;
    if (g < NBLK) blocksums[g] = 0.0;
}

// Load one tile's 4 contiguous B fragments + code half-norm into a named set.
#define LOADB(TOFF, P0, P1, P2, P3, HN)                                            \
  {                                                                                \
    const half8* _q = pb + (TOFF) * 1024;                                          \
    P0 = _q[0]; P1 = _q[1]; P2 = _q[2]; P3 = _q[3];                                \
    HN = ph[(TOFF) * 64];                                                          \
  }

// 6 chained MFMAs into ONE accumulator initialized with hn. MFMAs batched
// under setprio(1). Min-tracking packs the tile index into the 5 low
// mantissa bits (2 VALU/elem; perturbation <= 32 ulp ~ 1.2e-4 << belt).
#define VQ_STEP(P0, P1, P2, P3, HN, TT)                                            \
  {                                                                                \
    f32x4 acc[4];                                                                  \
    __builtin_amdgcn_s_setprio(1);                                                 \
    _Pragma("unroll")                                                              \
    for (int a = 0; a < 4; ++a) {                                                  \
      acc[a] = (f32x4){(HN), (HN), (HN), (HN)};                                    \
      acc[a] = __builtin_amdgcn_mfma_f32_16x16x32_f16(axh[a][0], P0, acc[a], 0, 0, 0); \
      acc[a] = __builtin_amdgcn_mfma_f32_16x16x32_f16(axh[a][1], P1, acc[a], 0, 0, 0); \
      acc[a] = __builtin_amdgcn_mfma_f32_16x16x32_f16(axl[a][0], P0, acc[a], 0, 0, 0); \
      acc[a] = __builtin_amdgcn_mfma_f32_16x16x32_f16(axl[a][1], P1, acc[a], 0, 0, 0); \
      acc[a] = __builtin_amdgcn_mfma_f32_16x16x32_f16(axh[a][0], P2, acc[a], 0, 0, 0); \
      acc[a] = __builtin_amdgcn_mfma_f32_16x16x32_f16(axh[a][1], P3, acc[a], 0, 0, 0); \
    }                                                                              \
    __builtin_amdgcn_s_setprio(0);                                                 \
    _Pragma("unroll")                                                              \
    for (int a = 0; a < 4; ++a)                                                    \
      _Pragma("unroll")                                                            \
      for (int r = 0; r < 4; ++r) {                                                \
        unsigned _kb = (__float_as_uint(acc[a][r]) & 0xFFFFFFE0u) | (unsigned)(TT);\
        best_d[a][r] = fminf(best_d[a][r], __uint_as_float(_kb));                  \
      }                                                                            \
  }

// Fused: one block = 64 tokens x ALL 2048 codes. Barrier-free main loop,
// THREE-buffer rotating register pipeline (unroll-3, fixed set names): each
// tile's loads issued two full VQ_STEPs (~1100 cy) before first use.
// __launch_bounds__(256, 2): min 2 waves/EU -> 256-VGPR budget. Every prior
// build landed at 92-100 VGPR (allocator targeting 5 waves/SIMD) and SANK
// the prefetch loads to their uses, deleting the pipeline; this trades
// occupancy we proved worthless (R5) for load-to-use distance.
__global__ __launch_bounds__(256, 2) void vq_fused(const float* __restrict__ x,
                                                   const float* __restrict__ emb,
                                                   const float* __restrict__ hnorm,
                                                   const half8* __restrict__ sw,
                                                   unsigned* __restrict__ counts,
                                                   double* __restrict__ blocksums,
                                                   float* __restrict__ out) {
    __shared__ unsigned long long kls[64][5];         // 4 candidates + pad
    __shared__ int bks[64];
    __shared__ double wsum[4];

    const int tid  = threadIdx.x;
    const int lane = tid & 63;
    const int wav  = tid >> 6;
    const int t0   = blockIdx.x * TOK_PER_BLK;
    const int m16  = lane & 15;             // A row (token) / B col (code)
    const int g    = lane >> 4;             // k-chunk group (0..3)
    const int ko   = g * 8;
    const int cit  = wav * 16 + m16;        // wave w owns codes [w*16, w*16+16)

    // A fragments: 4 a-tiles (the block's 64 tokens), negated hi/lo fp16 split
    half8 axh[4][2], axl[4][2];
#pragma unroll
    for (int a = 0; a < 4; ++a) {
        const float* xr = x + (size_t)(t0 + 16 * a + m16) * D;
#pragma unroll
        for (int c = 0; c < 2; ++c) {
            const float4* p4 = (const float4*)(xr + 32 * c + ko);
            float4 q0 = p4[0], q1 = p4[1];
            float v[8] = {q0.x, q0.y, q0.z, q0.w, q1.x, q1.y, q1.z, q1.w};
            half8 h, l;
#pragma unroll
            for (int j = 0; j < 8; ++j) {
                float nv = -v[j];
                _Float16 hh = (_Float16)nv;
                h[j] = hh;
                l[j] = (_Float16)(nv - (float)hh);
            }
            axh[a][c] = h; axl[a][c] = l;
        }
    }

    float best_d[4][4];                     // packed keys: dist w/ tile idx in low 5 bits
#pragma unroll
    for (int a = 0; a < 4; ++a)
#pragma unroll
        for (int r = 0; r < 4; ++r) best_d[a][r] = FLT_MAX;

    // per-lane streaming pointers: 64 B of fragments per lane per tile
    const half8* pb = sw + (size_t)tid * 4;           // tile stride = 1024 half8
    const float* ph = hnorm + cit;                    // tile stride = 64 floats

    half8 sA0, sA1, sA2, sA3;  float hA;   // set S0: tiles t = 0 mod 3
    half8 sB0, sB1, sB2, sB3;  float hB;   // set S1: tiles t = 1 mod 3
    half8 sC0, sC1, sC2, sC3;  float hC;   // set S2: tiles t = 2 mod 3

    // prologue: tiles 0,1 in flight
    LOADB(0, sA0, sA1, sA2, sA3, hA);
    LOADB(1, sB0, sB1, sB2, sB3, hB);

    // main loop: t = 0,3,...,27 (processes tiles 0..29; loads through 31, unguarded)
    for (int t = 0; t < 28; t += 3) {
        LOADB(2, sC0, sC1, sC2, sC3, hC);             // tile t+2, used 2 steps later
        VQ_STEP(sA0, sA1, sA2, sA3, hA, t);
        LOADB(3, sA0, sA1, sA2, sA3, hA);             // tile t+3
        VQ_STEP(sB0, sB1, sB2, sB3, hB, t + 1);
        LOADB(4, sB0, sB1, sB2, sB3, hB);             // tile t+4
        VQ_STEP(sC0, sC1, sC2, sC3, hC, t + 2);
        pb += 3 * 1024; ph += 3 * 64;
    }
    // tail: tiles 30 (in S0), 31 (in S1)
    VQ_STEP(sA0, sA1, sA2, sA3, hA, 30);
    VQ_STEP(sB0, sB1, sB2, sB3, hB, 31);

    // recover code from packed key; col-reduce over this wave's 16 columns
#pragma unroll
    for (int a = 0; a < 4; ++a)
#pragma unroll
        for (int r = 0; r < 4; ++r) {
            const unsigned bits = __float_as_uint(best_d[a][r]);
            const int code = (int)(bits & 31u) * TILE_C + cit;
            unsigned long long key = pack_key(best_d[a][r], code);
#pragma unroll
            for (int off = 8; off; off >>= 1) {
                unsigned long long o = shfl_xor_u64_w16(key, off);
                if (o < key) key = o;
            }
            if (m16 == 0) kls[16 * a + g * 4 + r][wav] = key;
        }
    __syncthreads();

    // merge the 4 wave-winners per token (wave 0, one lane per token)
    if (tid < 64) {
        float ds[4]; int kk[4];
        unsigned long long kmin = ~0ULL;
#pragma unroll
        for (int w = 0; w < 4; ++w) {
            unsigned long long key = kls[tid][w];
            ds[w] = unpack_dist(key);
            kk[w] = (int)(unsigned)(key & 0xFFFFFFFFu);
            if (key < kmin) kmin = key;
        }
        int bk = (int)(unsigned)(kmin & 0xFFFFFFFFu);
        const float fmin = unpack_dist(kmin);
        int cnt = 0;
#pragma unroll
        for (int w = 0; w < 4; ++w) cnt += (ds[w] <= fmin + EPS_RESCORE) ? 1 : 0;

        if (cnt > 1) {   // rare near-tie: exact fp32 rescore; packed-key min
            unsigned long long bkey = ~0ULL;   // smaller dist, tie smaller k
            const float* xr = x + (size_t)(t0 + tid) * D;
            for (int w = 0; w < 4; ++w) {
                if (ds[w] <= fmin + EPS_RESCORE) {
                    const int k = kk[w];
                    const float* cr = emb + (size_t)k * D;
                    float s0 = 0.f, s1 = 0.f, s2 = 0.f, s3 = 0.f;
#pragma unroll
                    for (int i = 0; i < 16; ++i) {
                        s0 = fmaf(cr[4 * i + 0], xr[4 * i + 0], s0);
                        s1 = fmaf(cr[4 * i + 1], xr[4 * i + 1], s1);
                        s2 = fmaf(cr[4 * i + 2], xr[4 * i + 2], s2);
                        s3 = fmaf(cr[4 * i + 3], xr[4 * i + 3], s3);
                    }
                    float hd = hnorm[k] - ((s0 + s1) + (s2 + s3));
                    unsigned long long key = pack_key(hd, k);
                    if (key < bkey) bkey = key;
                }
            }
            bk = (int)(unsigned)(bkey & 0xFFFFFFFFu);
        }
        bks[tid] = bk;
        out[IDX_OFF + t0 + tid] = (float)bk;
        atomicAdd(&counts[bk], 1u);
    }
    __syncthreads();

    // inline epilogue: quantize + sumsq (4 threads per token, coalesced)
    const int tok = tid >> 2;
    const int i4  = tid & 3;
    const int bk  = bks[tok];
    const float4* xr4 = (const float4*)(x + (size_t)(t0 + tok) * D);
    const float4* cr4 = (const float4*)(emb + (size_t)bk * D);
    float4* qr4 = (float4*)(out + (size_t)(t0 + tok) * D);
    float local = 0.f;
#pragma unroll
    for (int ii = 0; ii < 4; ++ii) {
        const int idx = i4 + 4 * ii;
        float4 xv = xr4[idx];
        float4 cv = cr4[idx];
        float dx = cv.x - xv.x, dy = cv.y - xv.y;
        float dz = cv.z - xv.z, dw = cv.w - xv.w;
        local += dx * dx + dy * dy + dz * dz + dw * dw;
        float4 q;
        q.x = xv.x + dx; q.y = xv.y + dy;   // straight-through: x + (q - x)
        q.z = xv.z + dz; q.w = xv.w + dw;
        qr4[idx] = q;
    }
    double ld = (double)local;
#pragma unroll
    for (int off = 32; off > 0; off >>= 1) ld += __shfl_down(ld, off, 64);
    if (lane == 0) wsum[wav] = ld;
    __syncthreads();
    if (tid == 0)
        blocksums[blockIdx.x] = (wsum[0] + wsum[1]) + (wsum[2] + wsum[3]);
}

__global__ __launch_bounds__(256) void vq_finalize(const unsigned* __restrict__ counts,
                                                   const double* __restrict__ blocksums,
                                                   float* __restrict__ out) {
    const int tid = threadIdx.x;
    double e = 0.0;
#pragma unroll
    for (int i = 0; i < 8; ++i) {
        int k = tid + i * 256;
        float p = (float)counts[k] / 65536.0f;
        out[PROB_OFF + k] = p;
        double pd = (double)p;
        e += pd * log(pd + 1e-5);
    }
    double s = 0.0;
#pragma unroll
    for (int i = 0; i < NBLK / 256; ++i) s += blocksums[tid + i * 256];
#pragma unroll
    for (int off = 32; off > 0; off >>= 1) {
        e += __shfl_down(e, off, 64);
        s += __shfl_down(s, off, 64);
    }
    __shared__ double we[4], ws2[4];
    int lane = tid & 63, wid = tid >> 6;
    if (lane == 0) { we[wid] = e; ws2[wid] = s; }
    __syncthreads();
    if (tid == 0) {
        double entropy = (we[0] + we[1]) + (we[2] + we[3]);
        double sumsq   = (ws2[0] + ws2[1]) + (ws2[2] + ws2[3]);
        double mse     = sumsq / (double)((size_t)N_TOK * D);
        out[SCAL_OFF + 0] = (float)(1.25 * mse + 0.1 * entropy); // vq_loss
        out[SCAL_OFF + 1] = (float)mse;                          // commitment_loss
        out[SCAL_OFF + 2] = (float)mse;                          // codebook_loss
        out[SCAL_OFF + 3] = (float)exp(-entropy);                // perplexity
        out[SCAL_OFF + 4] = (float)entropy;                      // entropy_loss
    }
}

extern "C" void kernel_launch(void* const* d_in, const int* in_sizes, int n_in,
                              void* d_out, int out_size, void* d_ws, size_t ws_size,
                              hipStream_t stream) {
    const float* x   = (const float*)d_in[0];
    const float* emb = (const float*)d_in[1];
    float* out = (float*)d_out;

    char* ws = (char*)d_ws;
    float*    hnorm     = (float*)(ws + WS_HNORM);
    unsigned* counts    = (unsigned*)(ws + WS_COUNT);
    double*   blocksums = (double*)(ws + WS_BSUM);
    half8*    sw        = (half8*)(ws + WS_SW);

    vq_init<<<K * 8 / 256, 256, 0, stream>>>(emb, hnorm, counts, blocksums, sw);
    vq_fused<<<NBLK, 256, 0, stream>>>(x, emb, hnorm, sw, counts, blocksums, out);
    vq_finalize<<<1, 256, 0, stream>>>(counts, blocksums, out);
}